// Round 6
// baseline (124.680 us; speedup 1.0000x reference)
//
#include <hip/hip_runtime.h>
#include <hip/hip_bf16.h>
#include <cmath>

#define NB 16384   // batch rows
#define NK 512     // in features
#define NO 1024    // out features (centres)
#define NC 5       // classes
#define NSL 16     // partial slices = 8 bn-blocks x 2 wave-cols
#define NT 16      // K-tiles (NK/32)

typedef float f32x4 __attribute__((ext_vector_type(4)));
typedef short s16x8 __attribute__((ext_vector_type(8)));
#define AS1 __attribute__((address_space(1)))
#define AS3 __attribute__((address_space(3)))

__device__ inline short f2bf(float f) {
    union { __hip_bfloat16 h; short s; } u;
    u.h = __float2bfloat16(f);
    return u.s;
}

// ---------------------------------------------------------------------------
// Kernel 1: fused row sum-of-squares (f32) + bf16 conversion of X and C.
// ---------------------------------------------------------------------------
__global__ void prep_bf16(const float* __restrict__ x, const float* __restrict__ c,
                          short* __restrict__ xbf, short* __restrict__ cbf,
                          float* __restrict__ x2, float* __restrict__ c2) {
    int gw   = (blockIdx.x * blockDim.x + threadIdx.x) >> 6;
    int lane = threadIdx.x & 63;
    if (gw >= NB + NO) return;
    bool isX = gw < NB;
    const float* src = isX ? (x + (size_t)gw * NK) : (c + (size_t)(gw - NB) * NK);
    short*       dst = isX ? (xbf + (size_t)gw * NK) : (cbf + (size_t)(gw - NB) * NK);
    f32x4 v0 = *(const f32x4*)(src + lane * 8);
    f32x4 v1 = *(const f32x4*)(src + lane * 8 + 4);
    s16x8 o;
    float s = 0.f;
#pragma unroll
    for (int j = 0; j < 4; ++j) {
        s += v0[j] * v0[j] + v1[j] * v1[j];
        o[j]     = f2bf(v0[j]);
        o[4 + j] = f2bf(v1[j]);
    }
    *(s16x8*)(dst + lane * 8) = o;
#pragma unroll
    for (int off = 1; off < 64; off <<= 1) s += __shfl_xor(s, off);
    if (lane == 0) {
        if (isX) x2[gw] = s;
        else     c2[gw - NB] = s;
    }
}

// Standalone prep for the fallback path.
__global__ void prep_f32(const float* __restrict__ x, const float* __restrict__ c,
                         float* __restrict__ x2, float* __restrict__ c2) {
    int gw   = (blockIdx.x * blockDim.x + threadIdx.x) >> 6;
    int lane = threadIdx.x & 63;
    if (gw >= NB + NO) return;
    const float* src = (gw < NB) ? (x + (size_t)gw * NK)
                                 : (c + (size_t)(gw - NB) * NK);
    f32x4 v0 = *(const f32x4*)(src + lane * 8);
    f32x4 v1 = *(const f32x4*)(src + lane * 8 + 4);
    float s = 0.f;
#pragma unroll
    for (int j = 0; j < 4; ++j) s += v0[j] * v0[j] + v1[j] * v1[j];
#pragma unroll
    for (int off = 1; off < 64; off <<= 1) s += __shfl_xor(s, off);
    if (lane == 0) {
        if (gw < NB) x2[gw] = s;
        else         c2[gw - NB] = s;
    }
}

// ---------------------------------------------------------------------------
// Kernel 2 (fallback only): out[b][n] = fc_b[n].
// ---------------------------------------------------------------------------
__global__ void init_out(float* __restrict__ out, const float* __restrict__ fcb) {
    int i = blockIdx.x * blockDim.x + threadIdx.x;
    if (i < NB * NC) out[i] = fcb[i % NC];
}

// ---------------------------------------------------------------------------
// Kernel 4: sum 16 partial slices + bias -> out.  part[NSL][NB*NC].
// ---------------------------------------------------------------------------
__global__ void reduce_out(const float* __restrict__ part,
                           const float* __restrict__ fcb,
                           float* __restrict__ out) {
    int i = blockIdx.x * blockDim.x + threadIdx.x;   // group of 4 f32
    if (i >= NB * NC / 4) return;
    f32x4 s = {0.f, 0.f, 0.f, 0.f};
#pragma unroll
    for (int sl = 0; sl < NSL; ++sl)
        s += *(const f32x4*)(part + (size_t)sl * NB * NC + i * 4);
    f32x4 o;
#pragma unroll
    for (int j = 0; j < 4; ++j) o[j] = s[j] + fcb[(i * 4 + j) % NC];
    *(f32x4*)(out + i * 4) = o;
}

// ---------------------------------------------------------------------------
// Kernel 3 (main): 256M x 128N tile, 512 threads = 8 waves (4M x 2N,
// per-wave 64x64), BK=32, 2 LDS buffers (48KB) -> 2 blocks/CU, grid 512 =
// all blocks resident. Catalog T3-minimum 2-phase: STAGE(t+1) -> ds_read(t)
// -> MFMA -> __syncthreads (vmcnt(0) drain covered by body + sibling block).
// Conflict-free LDS: physical 16B-chunk c holds logical chunk c ^ ((c>>3)&3)
// (pre-swizzled global source, linear gload_lds dest; reader XORs kg with
// (lr>>1)&3) -> 16-lane b128 reads spread over all 8 bank slots (2-way=free).
// ---------------------------------------------------------------------------
__global__ __launch_bounds__(512, 4)
void rbf_gemm_512(const short* __restrict__ Abf, const short* __restrict__ Bbf,
                  const float* __restrict__ x2, const float* __restrict__ c2,
                  const float* __restrict__ ls, const float* __restrict__ fcw,
                  float* __restrict__ part) {
    __shared__ short As[2][256 * 32];   // 2 x 16KB
    __shared__ short Bs[2][128 * 32];   // 2 x 8KB

    const int t    = threadIdx.x;
    const int lane = t & 63;
    const int wave = t >> 6;
    const int wr   = wave >> 1, wcn = wave & 1;   // 4M x 2N wave grid
    const int lr   = lane & 15, kg  = lane >> 4;

    // XCD-chunked remap: 512 blocks, 64 consecutive wg per XCD
    // -> per XCD: 8 bm x 8 bn => A-chunk 2MB + B 1MB in 4MB L2.
    const int orig = blockIdx.x;
    const int wg   = (orig & 7) * 64 + (orig >> 3);
    const int bm = wg >> 3, bn = wg & 7;

    // ---- staging: physical chunk c (16B) holds logical chunk c^((c>>3)&3) --
    const int l0   = t ^ ((t >> 3) & 3);     // logical chunk for phys chunk t
    const int srow = l0 >> 2;                // 0..127
    const int kc8  = (l0 & 3) * 8;           // short offset within row
    const short* gA0 = Abf + (size_t)(bm * 256 + srow) * NK + kc8;   // rows 0..127
    const short* gA1 = gA0 + (size_t)128 * NK;                        // rows 128..255
    const short* gB0 = Bbf + (size_t)(bn * 128 + srow) * NK + kc8;   // rows 0..127

#define STAGE(buf, kt) do {                                                     \
    __builtin_amdgcn_global_load_lds(                                           \
        (const AS1 unsigned int*)(gA0 + (kt) * 32),                             \
        (AS3 unsigned int*)(&As[buf][(size_t)t * 8]), 16, 0, 0);                \
    __builtin_amdgcn_global_load_lds(                                           \
        (const AS1 unsigned int*)(gA1 + (kt) * 32),                             \
        (AS3 unsigned int*)(&As[buf][(size_t)(512 + t) * 8]), 16, 0, 0);        \
    __builtin_amdgcn_global_load_lds(                                           \
        (const AS1 unsigned int*)(gB0 + (kt) * 32),                             \
        (AS3 unsigned int*)(&Bs[buf][(size_t)t * 8]), 16, 0, 0);                \
} while (0)

    // ---- fragment read offsets (swizzled) ----
    const int akoff = (kg ^ ((lr >> 1) & 3)) * 8;           // short offset
    const int arow0 = (wr * 64 + lr) * 32;                  // + mi*16*32
    const int brow0 = (wcn * 64 + lr) * 32;                 // + ni*16*32

    f32x4 acc[4][4];
#pragma unroll
    for (int i = 0; i < 4; ++i)
#pragma unroll
        for (int j = 0; j < 4; ++j)
#pragma unroll
            for (int k = 0; k < 4; ++k) acc[i][j][k] = 0.f;

    STAGE(0, 0);
    __syncthreads();
#pragma unroll
    for (int kt = 0; kt < NT; ++kt) {
        const int buf = kt & 1;
        if (kt + 1 < NT) STAGE(buf ^ 1, kt + 1);   // flies during this body
        s16x8 af[4], bfv[4];
#pragma unroll
        for (int ni = 0; ni < 4; ++ni)
            bfv[ni] = *(const s16x8*)(&Bs[buf][brow0 + ni * 512 + akoff]);
#pragma unroll
        for (int mi = 0; mi < 4; ++mi)
            af[mi]  = *(const s16x8*)(&As[buf][arow0 + mi * 512 + akoff]);
        __builtin_amdgcn_s_setprio(1);
#pragma unroll
        for (int mi = 0; mi < 4; ++mi)
#pragma unroll
            for (int ni = 0; ni < 4; ++ni)
                acc[mi][ni] = __builtin_amdgcn_mfma_f32_16x16x32_bf16(
                    af[mi], bfv[ni], acc[mi][ni], 0, 0, 0);
        __builtin_amdgcn_s_setprio(0);
        if (kt + 1 < NT) __syncthreads();          // drains vmcnt for t+1
    }
#undef STAGE

    // ---- epilogue: sq -> basis -> per-wave 64-col partial -> slice store ---
    // C frag (16x16x32): col = lane&15, row = (lane>>4)*4 + reg  [m89/m91]
    const int growb0 = bm * 256 + wr * 64 + kg * 4;   // + mi*16 + r
    const int gcol0  = bn * 128 + wcn * 64 + lr;      // + ni*16
    float* slice = part + (size_t)(bn * 2 + wcn) * NB * NC;

    float c2v[4], invs2[4], w[4][5];
#pragma unroll
    for (int ni = 0; ni < 4; ++ni) {
        int gc = gcol0 + ni * 16;
        c2v[ni]   = c2[gc];
        invs2[ni] = expf(-2.f * ls[gc]);   // 1/sigma^2; basis = exp(-sq/sigma^2)
#pragma unroll
        for (int n = 0; n < 5; ++n) w[ni][n] = fcw[n * NO + gc];
    }

#pragma unroll
    for (int mi = 0; mi < 4; ++mi) {
        float rs[4][5];
#pragma unroll
        for (int r = 0; r < 4; ++r)
#pragma unroll
            for (int n = 0; n < 5; ++n) rs[r][n] = 0.f;

#pragma unroll
        for (int r = 0; r < 4; ++r) {
            float x2v = x2[growb0 + mi * 16 + r];
#pragma unroll
            for (int ni = 0; ni < 4; ++ni) {
                float sq    = fmaxf(x2v + c2v[ni] - 2.f * acc[mi][ni][r], 0.f);
                float basis = expf(-sq * invs2[ni]);
#pragma unroll
                for (int n = 0; n < 5; ++n) rs[r][n] += basis * w[ni][n];
            }
        }
#pragma unroll
        for (int off = 1; off < 16; off <<= 1)
#pragma unroll
            for (int r = 0; r < 4; ++r)
#pragma unroll
                for (int n = 0; n < 5; ++n) rs[r][n] += __shfl_xor(rs[r][n], off);

        if (lr == 0) {
            float* dst = slice + (size_t)(growb0 + mi * 16) * NC;
            f32x4 v0 = {rs[0][0], rs[0][1], rs[0][2], rs[0][3]};
            f32x4 v1 = {rs[0][4], rs[1][0], rs[1][1], rs[1][2]};
            f32x4 v2 = {rs[1][3], rs[1][4], rs[2][0], rs[2][1]};
            f32x4 v3 = {rs[2][2], rs[2][3], rs[2][4], rs[3][0]};
            f32x4 v4 = {rs[3][1], rs[3][2], rs[3][3], rs[3][4]};
            *(f32x4*)(dst)      = v0;
            *(f32x4*)(dst + 4)  = v1;
            *(f32x4*)(dst + 8)  = v2;
            *(f32x4*)(dst + 12) = v3;
            *(f32x4*)(dst + 16) = v4;
        }
    }
}

// ---------------------------------------------------------------------------
// Fallback (ws too small): f32 reg-staged, atomic epilogue (round-1 proven).
// ---------------------------------------------------------------------------
__device__ inline void rbf_epilogue_atomic(f32x4 acc[4][4],
                                           const float* __restrict__ x2,
                                           const float* __restrict__ c2,
                                           const float* __restrict__ ls,
                                           const float* __restrict__ fcw,
                                           float* __restrict__ out,
                                           int bm, int bn, int wr, int wc,
                                           int lc, int kg) {
    const int growb0 = bm * 128 + wr * 64 + kg * 4;
    const int gcol0  = bn * 128 + wc * 64 + lc;
    float c2v[4], invs2[4], w[4][5];
#pragma unroll
    for (int ni = 0; ni < 4; ++ni) {
        int gc = gcol0 + ni * 16;
        c2v[ni]   = c2[gc];
        invs2[ni] = expf(-2.f * ls[gc]);
#pragma unroll
        for (int n = 0; n < 5; ++n) w[ni][n] = fcw[n * NO + gc];
    }
#pragma unroll
    for (int mi = 0; mi < 4; ++mi) {
        float rs[4][5];
#pragma unroll
        for (int r = 0; r < 4; ++r)
#pragma unroll
            for (int n = 0; n < 5; ++n) rs[r][n] = 0.f;
#pragma unroll
        for (int r = 0; r < 4; ++r) {
            float x2v = x2[growb0 + mi * 16 + r];
#pragma unroll
            for (int ni = 0; ni < 4; ++ni) {
                float sq    = fmaxf(x2v + c2v[ni] - 2.f * acc[mi][ni][r], 0.f);
                float basis = expf(-sq * invs2[ni]);
#pragma unroll
                for (int n = 0; n < 5; ++n) rs[r][n] += basis * w[ni][n];
            }
        }
#pragma unroll
        for (int off = 1; off < 16; off <<= 1)
#pragma unroll
            for (int r = 0; r < 4; ++r)
#pragma unroll
                for (int n = 0; n < 5; ++n) rs[r][n] += __shfl_xor(rs[r][n], off);
        if (lc == 0) {
#pragma unroll
            for (int r = 0; r < 4; ++r) {
                int grow = growb0 + mi * 16 + r;
#pragma unroll
                for (int n = 0; n < 5; ++n)
                    atomicAdd(&out[(size_t)grow * NC + n], rs[r][n]);
            }
        }
    }
}

__global__ __launch_bounds__(256)
void rbf_gemm_f32(const float* __restrict__ X, const float* __restrict__ Cn,
                  const float* __restrict__ x2, const float* __restrict__ c2,
                  const float* __restrict__ ls, const float* __restrict__ fcw,
                  float* __restrict__ out) {
    __shared__ short As[128 * 40];
    __shared__ short Bs[128 * 40];

    const int t    = threadIdx.x;
    const int lane = t & 63, wave = t >> 6;
    const int wr = wave >> 1, wc = wave & 1;
    const int lc = lane & 15, kg = lane >> 4;
    const int bn = blockIdx.x & 7, bm = blockIdx.x >> 3;

    const int srow = t >> 1, shalf = t & 1;
    const float* pA = X  + (size_t)(bm * 128 + srow) * NK + shalf * 16;
    const float* pB = Cn + (size_t)(bn * 128 + srow) * NK + shalf * 16;
    const int sbase = srow * 40 + shalf * 16;

    f32x4 ra[4], rb[4];
#pragma unroll
    for (int i = 0; i < 4; ++i) {
        ra[i] = *(const f32x4*)(pA + i * 4);
        rb[i] = *(const f32x4*)(pB + i * 4);
    }

    f32x4 acc[4][4];
#pragma unroll
    for (int i = 0; i < 4; ++i)
#pragma unroll
        for (int j = 0; j < 4; ++j)
#pragma unroll
            for (int k = 0; k < 4; ++k) acc[i][j][k] = 0.f;

    const short* Ab = As + (wr * 64 + lc) * 40 + kg * 8;
    const short* Bb = Bs + (wc * 64 + lc) * 40 + kg * 8;

    for (int kt = 0; kt < NK / 32; ++kt) {
        __syncthreads();
        s16x8 va0, va1, vb0, vb1;
#pragma unroll
        for (int i = 0; i < 8; ++i) {
            va0[i] = f2bf(ra[i >> 2][i & 3]);
            va1[i] = f2bf(ra[2 + (i >> 2)][i & 3]);
            vb0[i] = f2bf(rb[i >> 2][i & 3]);
            vb1[i] = f2bf(rb[2 + (i >> 2)][i & 3]);
        }
        *(s16x8*)&As[sbase]     = va0;
        *(s16x8*)&As[sbase + 8] = va1;
        *(s16x8*)&Bs[sbase]     = vb0;
        *(s16x8*)&Bs[sbase + 8] = vb1;
        __syncthreads();

        if (kt + 1 < NK / 32) {
            const float* qA = pA + (kt + 1) * 32;
            const float* qB = pB + (kt + 1) * 32;
#pragma unroll
            for (int i = 0; i < 4; ++i) {
                ra[i] = *(const f32x4*)(qA + i * 4);
                rb[i] = *(const f32x4*)(qB + i * 4);
            }
        }

        s16x8 af[4], bfv[4];
#pragma unroll
        for (int mi = 0; mi < 4; ++mi) af[mi]  = *(const s16x8*)(Ab + mi * 16 * 40);
#pragma unroll
        for (int ni = 0; ni < 4; ++ni) bfv[ni] = *(const s16x8*)(Bb + ni * 16 * 40);
#pragma unroll
        for (int mi = 0; mi < 4; ++mi)
#pragma unroll
            for (int ni = 0; ni < 4; ++ni)
                acc[mi][ni] = __builtin_amdgcn_mfma_f32_16x16x32_bf16(
                    af[mi], bfv[ni], acc[mi][ni], 0, 0, 0);
    }

    rbf_epilogue_atomic(acc, x2, c2, ls, fcw, out, bm, bn, wr, wc, lc, kg);
}

// ---------------------------------------------------------------------------
extern "C" void kernel_launch(void* const* d_in, const int* in_sizes, int n_in,
                              void* d_out, int out_size, void* d_ws, size_t ws_size,
                              hipStream_t stream) {
    const float* X   = (const float*)d_in[0];   // [16384, 512]
    const float* Cn  = (const float*)d_in[1];   // [1024, 512]
    const float* ls  = (const float*)d_in[2];   // [1024]
    const float* fcw = (const float*)d_in[3];   // [5, 1024]
    const float* fcb = (const float*)d_in[4];   // [5]
    float* out = (float*)d_out;                 // [16384, 5]

    const size_t xbf_e  = (size_t)NB * NK;          // shorts
    const size_t cbf_e  = (size_t)NO * NK;          // shorts
    const size_t part_e = (size_t)NSL * NB * NC;    // f32
    const size_t need   = (xbf_e + cbf_e) * 2 + (NB + NO) * 4 + part_e * 4;

    if (ws_size >= need) {
        short* xbf  = (short*)d_ws;
        short* cbf  = xbf + xbf_e;
        float* x2   = (float*)(cbf + cbf_e);
        float* c2   = x2 + NB;
        float* part = c2 + NO;
        prep_bf16<<<(NB + NO + 3) / 4, 256, 0, stream>>>(X, Cn, xbf, cbf, x2, c2);
        rbf_gemm_512<<<(NB / 256) * (NO / 128), 512, 0, stream>>>(xbf, cbf, x2, c2, ls, fcw, part);
        reduce_out<<<(NB * NC / 4 + 255) / 256, 256, 0, stream>>>(part, fcb, out);
    } else {
        float* x2 = (float*)d_ws;
        float* c2 = x2 + NB;
        init_out<<<(NB * NC + 255) / 256, 256, 0, stream>>>(out, fcb);
        prep_f32<<<(NB + NO + 3) / 4, 256, 0, stream>>>(X, Cn, x2, c2);
        rbf_gemm_f32<<<(NO / 128) * (NB / 128), 256, 0, stream>>>(X, Cn, x2, c2, ls, fcw, out);
    }
}

// Round 7
// 120.401 us; speedup vs baseline: 1.0355x; 1.0355x over previous
//
#include <hip/hip_runtime.h>
#include <hip/hip_bf16.h>
#include <cmath>

#define NB 16384   // batch rows
#define NK 512     // in features
#define NO 1024    // out features (centres)
#define NC 5       // classes
#define NSL 16     // partial slices = 4 bn-blocks x 4 wave-cols
#define NT 8       // K-tiles (NK/64)

typedef float f32x4 __attribute__((ext_vector_type(4)));
typedef short s16x8 __attribute__((ext_vector_type(8)));
#define AS1 __attribute__((address_space(1)))
#define AS3 __attribute__((address_space(3)))

__device__ inline short f2bf(float f) {
    union { __hip_bfloat16 h; short s; } u;
    u.h = __float2bfloat16(f);
    return u.s;
}

// ---------------------------------------------------------------------------
// Kernel 1: fused row sum-of-squares (f32) + bf16 conversion of X and C.
// ---------------------------------------------------------------------------
__global__ void prep_bf16(const float* __restrict__ x, const float* __restrict__ c,
                          short* __restrict__ xbf, short* __restrict__ cbf,
                          float* __restrict__ x2, float* __restrict__ c2) {
    int gw   = (blockIdx.x * blockDim.x + threadIdx.x) >> 6;
    int lane = threadIdx.x & 63;
    if (gw >= NB + NO) return;
    bool isX = gw < NB;
    const float* src = isX ? (x + (size_t)gw * NK) : (c + (size_t)(gw - NB) * NK);
    short*       dst = isX ? (xbf + (size_t)gw * NK) : (cbf + (size_t)(gw - NB) * NK);
    f32x4 v0 = *(const f32x4*)(src + lane * 8);
    f32x4 v1 = *(const f32x4*)(src + lane * 8 + 4);
    s16x8 o;
    float s = 0.f;
#pragma unroll
    for (int j = 0; j < 4; ++j) {
        s += v0[j] * v0[j] + v1[j] * v1[j];
        o[j]     = f2bf(v0[j]);
        o[4 + j] = f2bf(v1[j]);
    }
    *(s16x8*)(dst + lane * 8) = o;
#pragma unroll
    for (int off = 1; off < 64; off <<= 1) s += __shfl_xor(s, off);
    if (lane == 0) {
        if (isX) x2[gw] = s;
        else     c2[gw - NB] = s;
    }
}

// Standalone prep for the fallback path.
__global__ void prep_f32(const float* __restrict__ x, const float* __restrict__ c,
                         float* __restrict__ x2, float* __restrict__ c2) {
    int gw   = (blockIdx.x * blockDim.x + threadIdx.x) >> 6;
    int lane = threadIdx.x & 63;
    if (gw >= NB + NO) return;
    const float* src = (gw < NB) ? (x + (size_t)gw * NK)
                                 : (c + (size_t)(gw - NB) * NK);
    f32x4 v0 = *(const f32x4*)(src + lane * 8);
    f32x4 v1 = *(const f32x4*)(src + lane * 8 + 4);
    float s = 0.f;
#pragma unroll
    for (int j = 0; j < 4; ++j) s += v0[j] * v0[j] + v1[j] * v1[j];
#pragma unroll
    for (int off = 1; off < 64; off <<= 1) s += __shfl_xor(s, off);
    if (lane == 0) {
        if (gw < NB) x2[gw] = s;
        else         c2[gw - NB] = s;
    }
}

// ---------------------------------------------------------------------------
// Kernel 2 (fallback only): out[b][n] = fc_b[n].
// ---------------------------------------------------------------------------
__global__ void init_out(float* __restrict__ out, const float* __restrict__ fcb) {
    int i = blockIdx.x * blockDim.x + threadIdx.x;
    if (i < NB * NC) out[i] = fcb[i % NC];
}

// ---------------------------------------------------------------------------
// Kernel 4: sum 16 partial slices + bias -> out.  part[NSL][NB*NC].
// ---------------------------------------------------------------------------
__global__ void reduce_out(const float* __restrict__ part,
                           const float* __restrict__ fcb,
                           float* __restrict__ out) {
    int i = blockIdx.x * blockDim.x + threadIdx.x;   // group of 4 f32
    if (i >= NB * NC / 4) return;
    f32x4 s = {0.f, 0.f, 0.f, 0.f};
#pragma unroll
    for (int sl = 0; sl < NSL; ++sl)
        s += *(const f32x4*)(part + (size_t)sl * NB * NC + i * 4);
    f32x4 o;
#pragma unroll
    for (int j = 0; j < 4; ++j) o[j] = s[j] + fcb[(i * 4 + j) % NC];
    *(f32x4*)(out + i * 4) = o;
}

// ---------------------------------------------------------------------------
// Kernel 3 (main): m201-style 4-phase-per-K-tile schedule. 256x256 tile,
// BK=64, 2 dbuf (128KB LDS), 8 waves (2M x 4N, per-wave 128x64 C).
// Per K-tile: P1{12 ds_read + stage A(t+1); bar; lgkm0; MFMA Q00; bar}
//             P2{4 ds_read + stage B(t+1); bar; lgkm0; MFMA Q01; bar}
//             P3{8 ds_read;               bar; lgkm0; MFMA Q10; bar}
//             P4{MFMA Q11; vmcnt(0) (loads had ~2.5 phases to fly); bar}
// LDS swizzle (R6-verified conflict-free): physical 16B chunk within a
// 128B row holds logical chunk c ^ (row&7); pre-swizzled global source,
// linear gload_lds dest, swizzled ds_read (rule #21: both-sides).
// ---------------------------------------------------------------------------
__global__ __launch_bounds__(512, 2)
void rbf_gemm_8p(const short* __restrict__ Abf, const short* __restrict__ Bbf,
                 const float* __restrict__ x2, const float* __restrict__ c2,
                 const float* __restrict__ ls, const float* __restrict__ fcw,
                 float* __restrict__ part) {
    __shared__ short As[2][256 * 64];   // 2 x 32KB
    __shared__ short Bs[2][256 * 64];   // 2 x 32KB

    const int t    = threadIdx.x;
    const int lane = t & 63;
    const int wave = t >> 6;
    const int wr   = wave >> 2, wn = wave & 3;   // 2M x 4N wave grid
    const int lr   = lane & 15, kg = lane >> 4;

    // XCD-chunked remap: 256 blocks, 32 consecutive wg per XCD.
    const int orig = blockIdx.x;
    const int wg   = (orig & 7) * 32 + (orig >> 3);
    const int bm = wg >> 2, bn = wg & 3;

    // ---- staging addresses (pre-swizzled source, linear LDS dest) ----
    // phys chunk p = j*512 + t (16B each); row = p>>3; logical chunk-in-row
    // lc = (p&7) ^ (row&7).  t8 = LDS short-offset of chunk t within j-block.
    const int t8 = t * 8;
    const short* gAp[4];
    const short* gBp[4];
#pragma unroll
    for (int j = 0; j < 4; ++j) {
        int p   = j * 512 + t;
        int row = p >> 3;
        int lc  = (p & 7) ^ (row & 7);
        gAp[j] = Abf + (size_t)(bm * 256 + row) * NK + lc * 8;
        gBp[j] = Bbf + (size_t)(bn * 256 + row) * NK + lc * 8;
    }

    // ---- fragment-read offsets (swizzled) ----
    const int kc0 = ((kg)     ^ (lr & 7)) * 8;   // kslice 0 chunk
    const int kc1 = ((4 + kg) ^ (lr & 7)) * 8;   // kslice 1 chunk
    const int aoff0 = (wr * 128 + lr) * 64 + kc0;
    const int aoff1 = (wr * 128 + lr) * 64 + kc1;
    const int boff0 = (wn * 64 + lr) * 64 + kc0;
    const int boff1 = (wn * 64 + lr) * 64 + kc1;

    f32x4 acc[8][4];
#pragma unroll
    for (int i = 0; i < 8; ++i)
#pragma unroll
        for (int j = 0; j < 4; ++j)
#pragma unroll
            for (int k = 0; k < 4; ++k) acc[i][j][k] = 0.f;

    s16x8 aF[8], bF0[4], bF1[4];

#define STAGE_A(nb) do {                                                        \
    _Pragma("unroll")                                                           \
    for (int j = 0; j < 4; ++j)                                                 \
        __builtin_amdgcn_global_load_lds(                                       \
            (const AS1 unsigned int*)(gAp[j]),                                  \
            (AS3 unsigned int*)(&As[nb][j * 4096 + t8]), 16, 0, 0);             \
} while (0)

#define STAGE_B(nb) do {                                                        \
    _Pragma("unroll")                                                           \
    for (int j = 0; j < 4; ++j)                                                 \
        __builtin_amdgcn_global_load_lds(                                       \
            (const AS1 unsigned int*)(gBp[j]),                                  \
            (AS3 unsigned int*)(&Bs[nb][j * 4096 + t8]), 16, 0, 0);             \
} while (0)

#define ADVANCE() do {                                                          \
    _Pragma("unroll")                                                           \
    for (int j = 0; j < 4; ++j) { gAp[j] += 64; gBp[j] += 64; }                 \
} while (0)

#define RD_A(buf, mh) do {                                                      \
    _Pragma("unroll")                                                           \
    for (int mi2 = 0; mi2 < 4; ++mi2) {                                         \
        aF[mi2 * 2 + 0] = *(const s16x8*)(&As[buf][aoff0 + (mh) * 4096 + mi2 * 1024]); \
        aF[mi2 * 2 + 1] = *(const s16x8*)(&As[buf][aoff1 + (mh) * 4096 + mi2 * 1024]); \
    }                                                                           \
} while (0)

#define RD_B(buf, nh, dst) do {                                                 \
    _Pragma("unroll")                                                           \
    for (int nj = 0; nj < 2; ++nj) {                                            \
        dst[nj * 2 + 0] = *(const s16x8*)(&Bs[buf][boff0 + (nh) * 2048 + nj * 1024]); \
        dst[nj * 2 + 1] = *(const s16x8*)(&Bs[buf][boff1 + (nh) * 2048 + nj * 1024]); \
    }                                                                           \
} while (0)

#define MFMA_Q(mh, nh, breg) do {                                               \
    __builtin_amdgcn_s_setprio(1);                                              \
    _Pragma("unroll")                                                           \
    for (int mi2 = 0; mi2 < 4; ++mi2)                                           \
        _Pragma("unroll")                                                       \
        for (int nj = 0; nj < 2; ++nj) {                                        \
            f32x4 cc = acc[(mh) * 4 + mi2][(nh) * 2 + nj];                      \
            cc = __builtin_amdgcn_mfma_f32_16x16x32_bf16(aF[mi2 * 2 + 0], breg[nj * 2 + 0], cc, 0, 0, 0); \
            cc = __builtin_amdgcn_mfma_f32_16x16x32_bf16(aF[mi2 * 2 + 1], breg[nj * 2 + 1], cc, 0, 0, 0); \
            acc[(mh) * 4 + mi2][(nh) * 2 + nj] = cc;                            \
        }                                                                       \
    __builtin_amdgcn_s_setprio(0);                                              \
} while (0)

#define BAR()   __builtin_amdgcn_s_barrier()
#define LGKM0() do { asm volatile("s_waitcnt lgkmcnt(0)" ::: "memory"); \
                     __builtin_amdgcn_sched_barrier(0); } while (0)
#define VM0()   asm volatile("s_waitcnt vmcnt(0)" ::: "memory")

    // prologue: stage tile 0, drain, barrier
    STAGE_A(0); STAGE_B(0);
    ADVANCE();
    VM0(); BAR();

    for (int kt = 0; kt < NT; ++kt) {
        const int buf = kt & 1, nb = buf ^ 1;
        const bool nx = (kt + 1 < NT);
        // P1: 12 ds_read + stage A(t+1)
        RD_A(buf, 0); RD_B(buf, 0, bF0);
        if (nx) STAGE_A(nb);
        BAR(); LGKM0();
        MFMA_Q(0, 0, bF0);
        BAR();
        // P2: 4 ds_read + stage B(t+1)
        RD_B(buf, 1, bF1);
        if (nx) { STAGE_B(nb); ADVANCE(); }
        BAR(); LGKM0();
        MFMA_Q(0, 1, bF1);
        BAR();
        // P3: 8 ds_read
        RD_A(buf, 1);
        BAR(); LGKM0();
        MFMA_Q(1, 0, bF0);
        BAR();
        // P4: MFMA only; counted drain for next tile (loads flew ~2.5 phases)
        MFMA_Q(1, 1, bF1);
        if (nx) VM0();
        BAR();
    }

#undef STAGE_A
#undef STAGE_B
#undef ADVANCE
#undef RD_A
#undef RD_B
#undef MFMA_Q
#undef BAR
#undef LGKM0
#undef VM0

    // ---- epilogue: sq -> basis -> per-wave 64-col partial -> slice store ---
    // C frag (16x16x32): col = lane&15, row = (lane>>4)*4 + reg  [m89/m91]
    const int growb0 = bm * 256 + wr * 128 + kg * 4;  // + mi*16 + r
    const int gcol0  = bn * 256 + wn * 64 + lr;       // + ni*16
    float* slice = part + (size_t)(bn * 4 + wn) * NB * NC;

    float c2v[4], invs2[4], w[4][5];
#pragma unroll
    for (int ni = 0; ni < 4; ++ni) {
        int gc = gcol0 + ni * 16;
        c2v[ni]   = c2[gc];
        invs2[ni] = __expf(-2.f * ls[gc]);   // 1/sigma^2
#pragma unroll
        for (int n = 0; n < 5; ++n) w[ni][n] = fcw[n * NO + gc];
    }

#pragma unroll
    for (int mi = 0; mi < 8; ++mi) {
        float rs[4][5];
#pragma unroll
        for (int r = 0; r < 4; ++r)
#pragma unroll
            for (int n = 0; n < 5; ++n) rs[r][n] = 0.f;

#pragma unroll
        for (int r = 0; r < 4; ++r) {
            float x2v = x2[growb0 + mi * 16 + r];
#pragma unroll
            for (int ni = 0; ni < 4; ++ni) {
                float sq    = fmaxf(x2v + c2v[ni] - 2.f * acc[mi][ni][r], 0.f);
                float basis = __expf(-sq * invs2[ni]);
#pragma unroll
                for (int n = 0; n < 5; ++n) rs[r][n] += basis * w[ni][n];
            }
        }
#pragma unroll
        for (int off = 1; off < 16; off <<= 1)
#pragma unroll
            for (int r = 0; r < 4; ++r)
#pragma unroll
                for (int n = 0; n < 5; ++n) rs[r][n] += __shfl_xor(rs[r][n], off);

        if (lr == 0) {
            float* dst = slice + (size_t)(growb0 + mi * 16) * NC;
            f32x4 v0 = {rs[0][0], rs[0][1], rs[0][2], rs[0][3]};
            f32x4 v1 = {rs[0][4], rs[1][0], rs[1][1], rs[1][2]};
            f32x4 v2 = {rs[1][3], rs[1][4], rs[2][0], rs[2][1]};
            f32x4 v3 = {rs[2][2], rs[2][3], rs[2][4], rs[3][0]};
            f32x4 v4 = {rs[3][1], rs[3][2], rs[3][3], rs[3][4]};
            *(f32x4*)(dst)      = v0;
            *(f32x4*)(dst + 4)  = v1;
            *(f32x4*)(dst + 8)  = v2;
            *(f32x4*)(dst + 12) = v3;
            *(f32x4*)(dst + 16) = v4;
        }
    }
}

// ---------------------------------------------------------------------------
// Fallback (ws too small): f32 reg-staged, atomic epilogue (round-1 proven).
// ---------------------------------------------------------------------------
__device__ inline void rbf_epilogue_atomic(f32x4 acc[4][4],
                                           const float* __restrict__ x2,
                                           const float* __restrict__ c2,
                                           const float* __restrict__ ls,
                                           const float* __restrict__ fcw,
                                           float* __restrict__ out,
                                           int bm, int bn, int wr, int wc,
                                           int lc, int kg) {
    const int growb0 = bm * 128 + wr * 64 + kg * 4;
    const int gcol0  = bn * 128 + wc * 64 + lc;
    float c2v[4], invs2[4], w[4][5];
#pragma unroll
    for (int ni = 0; ni < 4; ++ni) {
        int gc = gcol0 + ni * 16;
        c2v[ni]   = c2[gc];
        invs2[ni] = expf(-2.f * ls[gc]);
#pragma unroll
        for (int n = 0; n < 5; ++n) w[ni][n] = fcw[n * NO + gc];
    }
#pragma unroll
    for (int mi = 0; mi < 4; ++mi) {
        float rs[4][5];
#pragma unroll
        for (int r = 0; r < 4; ++r)
#pragma unroll
            for (int n = 0; n < 5; ++n) rs[r][n] = 0.f;
#pragma unroll
        for (int r = 0; r < 4; ++r) {
            float x2v = x2[growb0 + mi * 16 + r];
#pragma unroll
            for (int ni = 0; ni < 4; ++ni) {
                float sq    = fmaxf(x2v + c2v[ni] - 2.f * acc[mi][ni][r], 0.f);
                float basis = expf(-sq * invs2[ni]);
#pragma unroll
                for (int n = 0; n < 5; ++n) rs[r][n] += basis * w[ni][n];
            }
        }
#pragma unroll
        for (int off = 1; off < 16; off <<= 1)
#pragma unroll
            for (int r = 0; r < 4; ++r)
#pragma unroll
                for (int n = 0; n < 5; ++n) rs[r][n] += __shfl_xor(rs[r][n], off);
        if (lc == 0) {
#pragma unroll
            for (int r = 0; r < 4; ++r) {
                int grow = growb0 + mi * 16 + r;
#pragma unroll
                for (int n = 0; n < 5; ++n)
                    atomicAdd(&out[(size_t)grow * NC + n], rs[r][n]);
            }
        }
    }
}

__global__ __launch_bounds__(256)
void rbf_gemm_f32(const float* __restrict__ X, const float* __restrict__ Cn,
                  const float* __restrict__ x2, const float* __restrict__ c2,
                  const float* __restrict__ ls, const float* __restrict__ fcw,
                  float* __restrict__ out) {
    __shared__ short As[128 * 40];
    __shared__ short Bs[128 * 40];

    const int t    = threadIdx.x;
    const int lane = t & 63, wave = t >> 6;
    const int wr = wave >> 1, wc = wave & 1;
    const int lc = lane & 15, kg = lane >> 4;
    const int bn = blockIdx.x & 7, bm = blockIdx.x >> 3;

    const int srow = t >> 1, shalf = t & 1;
    const float* pA = X  + (size_t)(bm * 128 + srow) * NK + shalf * 16;
    const float* pB = Cn + (size_t)(bn * 128 + srow) * NK + shalf * 16;
    const int sbase = srow * 40 + shalf * 16;

    f32x4 ra[4], rb[4];
#pragma unroll
    for (int i = 0; i < 4; ++i) {
        ra[i] = *(const f32x4*)(pA + i * 4);
        rb[i] = *(const f32x4*)(pB + i * 4);
    }

    f32x4 acc[4][4];
#pragma unroll
    for (int i = 0; i < 4; ++i)
#pragma unroll
        for (int j = 0; j < 4; ++j)
#pragma unroll
            for (int k = 0; k < 4; ++k) acc[i][j][k] = 0.f;

    const short* Ab = As + (wr * 64 + lc) * 40 + kg * 8;
    const short* Bb = Bs + (wc * 64 + lc) * 40 + kg * 8;

    for (int kt = 0; kt < NK / 32; ++kt) {
        __syncthreads();
        s16x8 va0, va1, vb0, vb1;
#pragma unroll
        for (int i = 0; i < 8; ++i) {
            va0[i] = f2bf(ra[i >> 2][i & 3]);
            va1[i] = f2bf(ra[2 + (i >> 2)][i & 3]);
            vb0[i] = f2bf(rb[i >> 2][i & 3]);
            vb1[i] = f2bf(rb[2 + (i >> 2)][i & 3]);
        }
        *(s16x8*)&As[sbase]     = va0;
        *(s16x8*)&As[sbase + 8] = va1;
        *(s16x8*)&Bs[sbase]     = vb0;
        *(s16x8*)&Bs[sbase + 8] = vb1;
        __syncthreads();

        if (kt + 1 < NK / 32) {
            const float* qA = pA + (kt + 1) * 32;
            const float* qB = pB + (kt + 1) * 32;
#pragma unroll
            for (int i = 0; i < 4; ++i) {
                ra[i] = *(const f32x4*)(qA + i * 4);
                rb[i] = *(const f32x4*)(qB + i * 4);
            }
        }

        s16x8 af[4], bfv[4];
#pragma unroll
        for (int mi = 0; mi < 4; ++mi) af[mi]  = *(const s16x8*)(Ab + mi * 16 * 40);
#pragma unroll
        for (int ni = 0; ni < 4; ++ni) bfv[ni] = *(const s16x8*)(Bb + ni * 16 * 40);
#pragma unroll
        for (int mi = 0; mi < 4; ++mi)
#pragma unroll
            for (int ni = 0; ni < 4; ++ni)
                acc[mi][ni] = __builtin_amdgcn_mfma_f32_16x16x32_bf16(
                    af[mi], bfv[ni], acc[mi][ni], 0, 0, 0);
    }

    rbf_epilogue_atomic(acc, x2, c2, ls, fcw, out, bm, bn, wr, wc, lc, kg);
}

// ---------------------------------------------------------------------------
extern "C" void kernel_launch(void* const* d_in, const int* in_sizes, int n_in,
                              void* d_out, int out_size, void* d_ws, size_t ws_size,
                              hipStream_t stream) {
    const float* X   = (const float*)d_in[0];   // [16384, 512]
    const float* Cn  = (const float*)d_in[1];   // [1024, 512]
    const float* ls  = (const float*)d_in[2];   // [1024]
    const float* fcw = (const float*)d_in[3];   // [5, 1024]
    const float* fcb = (const float*)d_in[4];   // [5]
    float* out = (float*)d_out;                 // [16384, 5]

    const size_t xbf_e  = (size_t)NB * NK;          // shorts
    const size_t cbf_e  = (size_t)NO * NK;          // shorts
    const size_t part_e = (size_t)NSL * NB * NC;    // f32
    const size_t need   = (xbf_e + cbf_e) * 2 + (NB + NO) * 4 + part_e * 4;

    if (ws_size >= need) {
        short* xbf  = (short*)d_ws;
        short* cbf  = xbf + xbf_e;
        float* x2   = (float*)(cbf + cbf_e);
        float* c2   = x2 + NB;
        float* part = c2 + NO;
        prep_bf16<<<(NB + NO + 3) / 4, 256, 0, stream>>>(X, Cn, xbf, cbf, x2, c2);
        rbf_gemm_8p<<<(NB / 256) * (NO / 256), 512, 0, stream>>>(xbf, cbf, x2, c2, ls, fcw, part);
        reduce_out<<<(NB * NC / 4 + 255) / 256, 256, 0, stream>>>(part, fcb, out);
    } else {
        float* x2 = (float*)d_ws;
        float* c2 = x2 + NB;
        init_out<<<(NB * NC + 255) / 256, 256, 0, stream>>>(out, fcb);
        prep_f32<<<(NB + NO + 3) / 4, 256, 0, stream>>>(X, Cn, x2, c2);
        rbf_gemm_f32<<<(NO / 128) * (NB / 128), 256, 0, stream>>>(X, Cn, x2, c2, ls, fcw, out);
    }
}